// Round 4
// baseline (734.613 us; speedup 1.0000x reference)
//
#include <hip/hip_runtime.h>

// 3-layer GCN, pull-mode CSR gather, aggregate-before-transform, prescaled features.
// CSR build = 2-pass bucketed counting sort (bucket = dst>>6, 64 nodes/bucket):
//   pass1: scatter (src,dst) pairs into per-bucket regions (monotonic cursors ->
//          dense line writes, ~1x write amplification)
//   pass2: one WG per bucket: LDS histogram(64) + wave shuffle-scan -> rowptr,
//          dinv, and csr placement (contiguous per-bucket region).

#define TPB 256
#define BSH 6  // 64 nodes per bucket

static inline int cdiv(long long a, int b) { return (int)((a + b - 1) / b); }

__global__ __launch_bounds__(TPB) void bhist_zero(int* __restrict__ bhist, int nb1) {
    int i = blockIdx.x * TPB + threadIdx.x;
    if (i < nb1) bhist[i] = 0;
}

__global__ __launch_bounds__(TPB) void bhist_kernel(const int* __restrict__ dst,
                                                    int* __restrict__ bhist, int e) {
    int i = blockIdx.x * TPB + threadIdx.x;
    if (i < e) atomicAdd(&bhist[dst[i] >> BSH], 1);
}

// single-block exclusive scan of bhist[nb] -> boff[0..nb], bcur copy (nb+1 <= 2048)
__global__ __launch_bounds__(TPB) void bscan(const int* __restrict__ bhist,
                                             int* __restrict__ boff,
                                             int* __restrict__ bcur, int nb) {
    __shared__ int lds[TPB];
    int tid = threadIdx.x;
    int base = tid * 8;
    int v[8], s = 0;
#pragma unroll
    for (int k = 0; k < 8; ++k) {
        v[k] = (base + k < nb) ? bhist[base + k] : 0;
        s += v[k];
    }
    lds[tid] = s;
    __syncthreads();
    for (int off = 1; off < TPB; off <<= 1) {
        int x = (tid >= off) ? lds[tid - off] : 0;
        __syncthreads();
        lds[tid] += x;
        __syncthreads();
    }
    int run = lds[tid] - s;  // exclusive
#pragma unroll
    for (int k = 0; k < 8; ++k) {
        if (base + k <= nb) { boff[base + k] = run; bcur[base + k] = run; }
        run += v[k];
    }
}

__global__ __launch_bounds__(TPB) void bucket_fill(const int* __restrict__ src,
                                                   const int* __restrict__ dst,
                                                   int* __restrict__ bcur,
                                                   int2* __restrict__ pairs, int e) {
    int i = blockIdx.x * TPB + threadIdx.x;
    if (i >= e) return;
    int s = src[i], d = dst[i];
    int pos = atomicAdd(&bcur[d >> BSH], 1);
    pairs[pos] = make_int2(s, d);
}

// one WG per bucket: histogram -> scan -> rowptr/dinv -> csr placement
__global__ __launch_bounds__(TPB) void build_csr(const int2* __restrict__ pairs,
                                                 const int* __restrict__ boff,
                                                 int* __restrict__ rowptr,
                                                 float* __restrict__ dinv,
                                                 int* __restrict__ csr, int n, int e) {
    int b = blockIdx.x;
    int p0 = boff[b], p1 = boff[b + 1];
    __shared__ int scnt[64];
    __shared__ int sbase[64];
    int tid = threadIdx.x;
    if (tid < 64) scnt[tid] = 0;
    __syncthreads();
    for (int j = p0 + tid; j < p1; j += TPB)
        atomicAdd(&scnt[pairs[j].y & 63], 1);
    __syncthreads();
    if (tid < 64) {  // wave 0: shuffle inclusive scan over 64 counters
        int c = scnt[tid];
        int v = c;
#pragma unroll
        for (int d = 1; d < 64; d <<= 1) {
            int t = __shfl_up(v, d);
            if (tid >= d) v += t;
        }
        int excl = v - c;
        sbase[tid] = p0 + excl;
        int node = (b << BSH) + tid;
        if (node < n) {
            rowptr[node] = p0 + excl;
            dinv[node] = rsqrtf(1.0f + (float)c);  // +1 self-loop
        }
    }
    if (b == 0 && tid == 0) rowptr[n] = e;
    __syncthreads();
    for (int j = p0 + tid; j < p1; j += TPB) {
        int2 pr = pairs[j];
        int pos = atomicAdd(&sbase[pr.y & 63], 1);
        csr[pos] = pr.x;
    }
}

// xs[i][k] = x[i][k] * dinv[i]
template <int K>
__global__ __launch_bounds__(TPB) void prescale(const float* __restrict__ x,
                                                const float* __restrict__ dinv,
                                                float* __restrict__ xs, int n) {
    int idx = blockIdx.x * TPB + threadIdx.x;
    if (idx < n * K) xs[idx] = x[idx] * dinv[idx / K];
}

// ---- aggregation: C lanes per node, unroll-8 gather, one coalesced write ----
template <int C>
__global__ __launch_bounds__(TPB) void agg_kernel(const float* __restrict__ hs,
                                                  const int* __restrict__ rowptr,
                                                  const int* __restrict__ csr,
                                                  const float* __restrict__ dinv,
                                                  float* __restrict__ agg, int n) {
    const int NPB = TPB / C;
    int grp = threadIdx.x / C, c = threadIdx.x % C;
    int i = blockIdx.x * NPB + grp;
    if (i >= n) return;
    int j = rowptr[i], re = rowptr[i + 1];
    float acc = hs[(size_t)i * C + c];  // self-loop term
    float acc2 = 0.0f;
    for (; j + 8 <= re; j += 8) {
        int s0 = csr[j + 0], s1 = csr[j + 1], s2 = csr[j + 2], s3 = csr[j + 3];
        int s4 = csr[j + 4], s5 = csr[j + 5], s6 = csr[j + 6], s7 = csr[j + 7];
        float v0 = hs[(size_t)s0 * C + c], v1 = hs[(size_t)s1 * C + c];
        float v2 = hs[(size_t)s2 * C + c], v3 = hs[(size_t)s3 * C + c];
        float v4 = hs[(size_t)s4 * C + c], v5 = hs[(size_t)s5 * C + c];
        float v6 = hs[(size_t)s6 * C + c], v7 = hs[(size_t)s7 * C + c];
        acc  += (v0 + v1) + (v2 + v3);
        acc2 += (v4 + v5) + (v6 + v7);
    }
    if (j + 4 <= re) {
        int s0 = csr[j + 0], s1 = csr[j + 1], s2 = csr[j + 2], s3 = csr[j + 3];
        acc  += hs[(size_t)s0 * C + c] + hs[(size_t)s1 * C + c];
        acc2 += hs[(size_t)s2 * C + c] + hs[(size_t)s3 * C + c];
        j += 4;
    }
    for (; j < re; ++j) acc += hs[(size_t)csr[j] * C + c];
    agg[(size_t)i * C + c] = (acc + acc2) * dinv[i];
}

// ---- dense transform: out[i][c] = (relu?)( in[i]@W + b )[c] * (dinv[i] if SCALE) ----
template <int K, int C, bool RELU_OUT, bool SCALE_OUT>
__global__ __launch_bounds__(TPB) void xw_kernel(const float* __restrict__ in,
                                                 const float* __restrict__ W,
                                                 const float* __restrict__ b,
                                                 const float* __restrict__ dinv,
                                                 float* __restrict__ out, int n) {
    __shared__ float sW[K * C];
    for (int t = threadIdx.x; t < K * C; t += TPB) sW[t] = W[t];
    __syncthreads();
    int idx = blockIdx.x * TPB + threadIdx.x;
    int i = idx / C, c = idx % C;
    if (i >= n) return;
    float acc = b[c];
#pragma unroll
    for (int k = 0; k < K; ++k)
        acc = fmaf(in[(size_t)i * K + k], sW[k * C + c], acc);
    if (RELU_OUT) acc = fmaxf(acc, 0.0f);
    if (SCALE_OUT) acc *= dinv[i];
    out[idx] = acc;
}

extern "C" void kernel_launch(void* const* d_in, const int* in_sizes, int n_in,
                              void* d_out, int out_size, void* d_ws, size_t ws_size,
                              hipStream_t stream) {
    const float* x  = (const float*)d_in[0];
    const int*   ei = (const int*)d_in[1];
    const float* W1 = (const float*)d_in[2];
    const float* b1 = (const float*)d_in[3];
    const float* W2 = (const float*)d_in[4];
    const float* b2 = (const float*)d_in[5];
    const float* W3 = (const float*)d_in[6];
    const float* b3 = (const float*)d_in[7];
    float* out = (float*)d_out;

    const int n = in_sizes[0] / 4;   // 100000
    const int e = in_sizes[1] / 2;   // 1600000
    const int* src = ei;
    const int* dst = ei + e;
    const int nb = cdiv(n, 1 << BSH);  // 1563 buckets

    char* ws = (char*)d_ws;
    size_t off = 0;
    auto carve = [&](size_t bytes) {
        char* p = ws + off;
        off = (off + bytes + 255) & ~(size_t)255;
        return p;
    };
    float* dinv   = (float*)carve((size_t)n * 4);
    int*   rowptr = (int*)  carve((size_t)(n + 1) * 4);
    int*   bhist  = (int*)  carve((size_t)(nb + 1) * 4);
    int*   boff   = (int*)  carve((size_t)(nb + 1) * 4);
    int*   bcur   = (int*)  carve((size_t)(nb + 1) * 4);
    int*   csr    = (int*)  carve((size_t)e * 4);
    float* A      = (float*)carve((size_t)n * 64 * 4);  // agg output; pairs aliases this
    float* B      = (float*)carve((size_t)n * 32 * 4);  // h1s
    float* xs     = (float*)carve((size_t)n * 4 * 4);   // prescaled x
    int2* pairs = (int2*)A;  // 12.8 MB <= 25.6 MB; consumed before A is first written

    // ---- CSR + norms (bucketed counting sort) ----
    bhist_zero<<<cdiv(nb + 1, TPB), TPB, 0, stream>>>(bhist, nb + 1);
    bhist_kernel<<<cdiv(e, TPB), TPB, 0, stream>>>(dst, bhist, e);
    bscan<<<1, TPB, 0, stream>>>(bhist, boff, bcur, nb);
    bucket_fill<<<cdiv(e, TPB), TPB, 0, stream>>>(src, dst, bcur, pairs, e);
    build_csr<<<nb, TPB, 0, stream>>>(pairs, boff, rowptr, dinv, csr, n, e);

    // ---- layer 1: xs = x*dinv; agg C=4; h1s = relu(agg@W1+b1)*dinv [n,32] ----
    prescale<4><<<cdiv((long long)n * 4, TPB), TPB, 0, stream>>>(x, dinv, xs, n);
    agg_kernel<4><<<cdiv(n, TPB / 4), TPB, 0, stream>>>(xs, rowptr, csr, dinv, A, n);
    xw_kernel<4, 32, true, true><<<cdiv((long long)n * 32, TPB), TPB, 0, stream>>>(A, W1, b1, dinv, B, n);

    // ---- layer 2: agg C=32; h2s = relu(agg@W2+b2)*dinv [n,64] (in d_out) ----
    agg_kernel<32><<<cdiv(n, TPB / 32), TPB, 0, stream>>>(B, rowptr, csr, dinv, A, n);
    xw_kernel<32, 64, true, true><<<cdiv((long long)n * 64, TPB), TPB, 0, stream>>>(A, W2, b2, dinv, out, n);

    // ---- layer 3: agg C=64; out = agg@W3+b3 ----
    agg_kernel<64><<<cdiv(n, TPB / 64), TPB, 0, stream>>>(out, rowptr, csr, dinv, A, n);
    xw_kernel<64, 64, false, false><<<cdiv((long long)n * 64, TPB), TPB, 0, stream>>>(A, W3, b3, dinv, out, n);
}

// Round 5
// 295.088 us; speedup vs baseline: 2.4895x; 2.4895x over previous
//
#include <hip/hip_runtime.h>

// 3-layer GCN, pull-mode CSR gather, aggregate-before-transform, prescaled features.
// CSR build = 2-pass LDS-staged multisplit counting sort (bucket = dst>>8, 256
// nodes/bucket, nb=391):
//   ms_hist:    per-block LDS histogram -> <=512 global atomics per block
//   bscan:      single-block scan of 512 bucket counts -> boff/bcur
//   ms_scatter: per-block LDS histogram + per-bucket run reservation
//               (one global atomic per (block,bucket)) -> contiguous ~168B runs
//   build_csr:  one WG per bucket: LDS hist(256) + scan -> rowptr, dinv, csr.

#define TPB 256
#define BSH 8                 // 256 nodes per bucket
#define NBMAX 512             // LDS histogram slots (nb = 391 actual)
#define IPT 32                // edges per thread -> 8192 edges per block

static inline int cdiv(long long a, int b) { return (int)((a + b - 1) / b); }

__global__ __launch_bounds__(TPB) void bhist_zero(int* __restrict__ bhist, int m) {
    int i = blockIdx.x * TPB + threadIdx.x;
    if (i < m) bhist[i] = 0;
}

__global__ __launch_bounds__(TPB) void ms_hist(const int* __restrict__ dst,
                                               int* __restrict__ bhist, int e) {
    __shared__ int h[NBMAX];
    int tid = threadIdx.x;
    h[tid] = 0; h[tid + TPB] = 0;
    __syncthreads();
    int base = blockIdx.x * (TPB * IPT);
#pragma unroll 8
    for (int k = 0; k < IPT; ++k) {
        int i = base + k * TPB + tid;
        if (i < e) atomicAdd(&h[dst[i] >> BSH], 1);
    }
    __syncthreads();
    int v0 = h[tid], v1 = h[tid + TPB];
    if (v0) atomicAdd(&bhist[tid], v0);
    if (v1) atomicAdd(&bhist[tid + TPB], v1);
}

// single-block exclusive scan of bhist[NBMAX] -> boff/bcur[0..NBMAX]
__global__ __launch_bounds__(TPB) void bscan(const int* __restrict__ bhist,
                                             int* __restrict__ boff,
                                             int* __restrict__ bcur) {
    __shared__ int lds[TPB];
    int tid = threadIdx.x;
    int a = bhist[2 * tid], b = bhist[2 * tid + 1];
    int s = a + b;
    lds[tid] = s;
    __syncthreads();
    for (int off = 1; off < TPB; off <<= 1) {
        int x = (tid >= off) ? lds[tid - off] : 0;
        __syncthreads();
        lds[tid] += x;
        __syncthreads();
    }
    int excl = lds[tid] - s;
    boff[2 * tid] = excl;       bcur[2 * tid] = excl;
    boff[2 * tid + 1] = excl + a; bcur[2 * tid + 1] = excl + a;
    if (tid == TPB - 1) { boff[NBMAX] = lds[TPB - 1]; bcur[NBMAX] = lds[TPB - 1]; }
}

__global__ __launch_bounds__(TPB) void ms_scatter(const int* __restrict__ src,
                                                  const int* __restrict__ dst,
                                                  int* __restrict__ bcur,
                                                  int2* __restrict__ pairs, int e) {
    __shared__ int h[NBMAX];
    __shared__ int sbase[NBMAX];
    int tid = threadIdx.x;
    h[tid] = 0; h[tid + TPB] = 0;
    __syncthreads();
    int base = blockIdx.x * (TPB * IPT);
#pragma unroll 8
    for (int k = 0; k < IPT; ++k) {
        int i = base + k * TPB + tid;
        if (i < e) atomicAdd(&h[dst[i] >> BSH], 1);
    }
    __syncthreads();
    int v0 = h[tid], v1 = h[tid + TPB];
    if (v0) sbase[tid] = atomicAdd(&bcur[tid], v0);
    if (v1) sbase[tid + TPB] = atomicAdd(&bcur[tid + TPB], v1);
    __syncthreads();
#pragma unroll 8
    for (int k = 0; k < IPT; ++k) {
        int i = base + k * TPB + tid;
        if (i < e) {
            int s = src[i], d = dst[i];
            int pos = atomicAdd(&sbase[d >> BSH], 1);
            pairs[pos] = make_int2(s, d);
        }
    }
}

// one WG per bucket: histogram -> scan -> rowptr/dinv -> csr placement
__global__ __launch_bounds__(TPB) void build_csr(const int2* __restrict__ pairs,
                                                 const int* __restrict__ boff,
                                                 int* __restrict__ rowptr,
                                                 float* __restrict__ dinv,
                                                 int* __restrict__ csr, int n, int e) {
    int b = blockIdx.x;
    int p0 = boff[b], p1 = boff[b + 1];
    __shared__ int scnt[TPB];
    __shared__ int sbase[TPB];
    __shared__ int lds[TPB];
    int tid = threadIdx.x;
    scnt[tid] = 0;
    __syncthreads();
    for (int j = p0 + tid; j < p1; j += TPB)
        atomicAdd(&scnt[pairs[j].y & (TPB - 1)], 1);
    __syncthreads();
    int c = scnt[tid];
    lds[tid] = c;
    __syncthreads();
    for (int off = 1; off < TPB; off <<= 1) {
        int x = (tid >= off) ? lds[tid - off] : 0;
        __syncthreads();
        lds[tid] += x;
        __syncthreads();
    }
    int excl = lds[tid] - c;
    sbase[tid] = p0 + excl;
    int node = (b << BSH) + tid;
    if (node < n) {
        rowptr[node] = p0 + excl;
        dinv[node] = rsqrtf(1.0f + (float)c);  // +1 self-loop
    }
    if (b == 0 && tid == 0) rowptr[n] = e;
    __syncthreads();
    for (int j = p0 + tid; j < p1; j += TPB) {
        int2 pr = pairs[j];
        int pos = atomicAdd(&sbase[pr.y & (TPB - 1)], 1);
        csr[pos] = pr.x;
    }
}

// xs[i][k] = x[i][k] * dinv[i]
template <int K>
__global__ __launch_bounds__(TPB) void prescale(const float* __restrict__ x,
                                                const float* __restrict__ dinv,
                                                float* __restrict__ xs, int n) {
    int idx = blockIdx.x * TPB + threadIdx.x;
    if (idx < n * K) xs[idx] = x[idx] * dinv[idx / K];
}

// ---- aggregation: C lanes per node, unroll-8 gather, one coalesced write ----
template <int C>
__global__ __launch_bounds__(TPB) void agg_kernel(const float* __restrict__ hs,
                                                  const int* __restrict__ rowptr,
                                                  const int* __restrict__ csr,
                                                  const float* __restrict__ dinv,
                                                  float* __restrict__ agg, int n) {
    const int NPB = TPB / C;
    int grp = threadIdx.x / C, c = threadIdx.x % C;
    int i = blockIdx.x * NPB + grp;
    if (i >= n) return;
    int j = rowptr[i], re = rowptr[i + 1];
    float acc = hs[(size_t)i * C + c];  // self-loop term
    float acc2 = 0.0f;
    for (; j + 8 <= re; j += 8) {
        int s0 = csr[j + 0], s1 = csr[j + 1], s2 = csr[j + 2], s3 = csr[j + 3];
        int s4 = csr[j + 4], s5 = csr[j + 5], s6 = csr[j + 6], s7 = csr[j + 7];
        float v0 = hs[(size_t)s0 * C + c], v1 = hs[(size_t)s1 * C + c];
        float v2 = hs[(size_t)s2 * C + c], v3 = hs[(size_t)s3 * C + c];
        float v4 = hs[(size_t)s4 * C + c], v5 = hs[(size_t)s5 * C + c];
        float v6 = hs[(size_t)s6 * C + c], v7 = hs[(size_t)s7 * C + c];
        acc  += (v0 + v1) + (v2 + v3);
        acc2 += (v4 + v5) + (v6 + v7);
    }
    if (j + 4 <= re) {
        int s0 = csr[j + 0], s1 = csr[j + 1], s2 = csr[j + 2], s3 = csr[j + 3];
        acc  += hs[(size_t)s0 * C + c] + hs[(size_t)s1 * C + c];
        acc2 += hs[(size_t)s2 * C + c] + hs[(size_t)s3 * C + c];
        j += 4;
    }
    for (; j < re; ++j) acc += hs[(size_t)csr[j] * C + c];
    agg[(size_t)i * C + c] = (acc + acc2) * dinv[i];
}

// ---- dense transform: out[i][c] = (relu?)( in[i]@W + b )[c] * (dinv[i] if SCALE) ----
template <int K, int C, bool RELU_OUT, bool SCALE_OUT>
__global__ __launch_bounds__(TPB) void xw_kernel(const float* __restrict__ in,
                                                 const float* __restrict__ W,
                                                 const float* __restrict__ b,
                                                 const float* __restrict__ dinv,
                                                 float* __restrict__ out, int n) {
    __shared__ float sW[K * C];
    for (int t = threadIdx.x; t < K * C; t += TPB) sW[t] = W[t];
    __syncthreads();
    int idx = blockIdx.x * TPB + threadIdx.x;
    int i = idx / C, c = idx % C;
    if (i >= n) return;
    float acc = b[c];
#pragma unroll
    for (int k = 0; k < K; ++k)
        acc = fmaf(in[(size_t)i * K + k], sW[k * C + c], acc);
    if (RELU_OUT) acc = fmaxf(acc, 0.0f);
    if (SCALE_OUT) acc *= dinv[i];
    out[idx] = acc;
}

extern "C" void kernel_launch(void* const* d_in, const int* in_sizes, int n_in,
                              void* d_out, int out_size, void* d_ws, size_t ws_size,
                              hipStream_t stream) {
    const float* x  = (const float*)d_in[0];
    const int*   ei = (const int*)d_in[1];
    const float* W1 = (const float*)d_in[2];
    const float* b1 = (const float*)d_in[3];
    const float* W2 = (const float*)d_in[4];
    const float* b2 = (const float*)d_in[5];
    const float* W3 = (const float*)d_in[6];
    const float* b3 = (const float*)d_in[7];
    float* out = (float*)d_out;

    const int n = in_sizes[0] / 4;   // 100000
    const int e = in_sizes[1] / 2;   // 1600000
    const int* src = ei;
    const int* dst = ei + e;
    const int nb = cdiv(n, 1 << BSH);  // 391 buckets (NBMAX=512 slots)

    char* ws = (char*)d_ws;
    size_t off = 0;
    auto carve = [&](size_t bytes) {
        char* p = ws + off;
        off = (off + bytes + 255) & ~(size_t)255;
        return p;
    };
    float* dinv   = (float*)carve((size_t)n * 4);
    int*   rowptr = (int*)  carve((size_t)(n + 1) * 4);
    int*   bhist  = (int*)  carve((size_t)(NBMAX + 1) * 4);
    int*   boff   = (int*)  carve((size_t)(NBMAX + 1) * 4);
    int*   bcur   = (int*)  carve((size_t)(NBMAX + 1) * 4);
    int*   csr    = (int*)  carve((size_t)e * 4);
    float* A      = (float*)carve((size_t)n * 64 * 4);  // agg output; pairs aliases this
    float* B      = (float*)carve((size_t)n * 32 * 4);  // h1s
    float* xs     = (float*)carve((size_t)n * 4 * 4);   // prescaled x
    int2* pairs = (int2*)A;  // 12.8 MB <= 25.6 MB; consumed before A is first written

    const int eblk = cdiv(e, TPB * IPT);  // 196 blocks over edges

    // ---- CSR + norms (LDS-staged multisplit counting sort) ----
    bhist_zero<<<cdiv(NBMAX + 1, TPB), TPB, 0, stream>>>(bhist, NBMAX + 1);
    ms_hist<<<eblk, TPB, 0, stream>>>(dst, bhist, e);
    bscan<<<1, TPB, 0, stream>>>(bhist, boff, bcur);
    ms_scatter<<<eblk, TPB, 0, stream>>>(src, dst, bcur, pairs, e);
    build_csr<<<nb, TPB, 0, stream>>>(pairs, boff, rowptr, dinv, csr, n, e);

    // ---- layer 1: xs = x*dinv; agg C=4; h1s = relu(agg@W1+b1)*dinv [n,32] ----
    prescale<4><<<cdiv((long long)n * 4, TPB), TPB, 0, stream>>>(x, dinv, xs, n);
    agg_kernel<4><<<cdiv(n, TPB / 4), TPB, 0, stream>>>(xs, rowptr, csr, dinv, A, n);
    xw_kernel<4, 32, true, true><<<cdiv((long long)n * 32, TPB), TPB, 0, stream>>>(A, W1, b1, dinv, B, n);

    // ---- layer 2: agg C=32; h2s = relu(agg@W2+b2)*dinv [n,64] (in d_out) ----
    agg_kernel<32><<<cdiv(n, TPB / 32), TPB, 0, stream>>>(B, rowptr, csr, dinv, A, n);
    xw_kernel<32, 64, true, true><<<cdiv((long long)n * 64, TPB), TPB, 0, stream>>>(A, W2, b2, dinv, out, n);

    // ---- layer 3: agg C=64; out = agg@W3+b3 ----
    agg_kernel<64><<<cdiv(n, TPB / 64), TPB, 0, stream>>>(out, rowptr, csr, dinv, A, n);
    xw_kernel<64, 64, false, false><<<cdiv((long long)n * 64, TPB), TPB, 0, stream>>>(A, W3, b3, dinv, out, n);
}

// Round 6
// 276.776 us; speedup vs baseline: 2.6542x; 1.0662x over previous
//
#include <hip/hip_runtime.h>

// 3-layer GCN, pull-mode CSR gather, aggregate-before-transform, prescaled features.
// CSR build = 2-pass LDS-staged multisplit counting sort (bucket = dst>>8).
// xw transform: W-column held in VGPRs (no LDS), 4 nodes/thread for ILP,
// broadcast float4 row loads, coalesced stores.

#define TPB 256
#define BSH 8                 // 256 nodes per bucket
#define NBMAX 512             // LDS histogram slots (nb = 391 actual)
#define IPT 32                // edges per thread -> 8192 edges per block

static inline int cdiv(long long a, int b) { return (int)((a + b - 1) / b); }

__global__ __launch_bounds__(TPB) void bhist_zero(int* __restrict__ bhist, int m) {
    int i = blockIdx.x * TPB + threadIdx.x;
    if (i < m) bhist[i] = 0;
}

__global__ __launch_bounds__(TPB) void ms_hist(const int* __restrict__ dst,
                                               int* __restrict__ bhist, int e) {
    __shared__ int h[NBMAX];
    int tid = threadIdx.x;
    h[tid] = 0; h[tid + TPB] = 0;
    __syncthreads();
    int base = blockIdx.x * (TPB * IPT);
#pragma unroll 8
    for (int k = 0; k < IPT; ++k) {
        int i = base + k * TPB + tid;
        if (i < e) atomicAdd(&h[dst[i] >> BSH], 1);
    }
    __syncthreads();
    int v0 = h[tid], v1 = h[tid + TPB];
    if (v0) atomicAdd(&bhist[tid], v0);
    if (v1) atomicAdd(&bhist[tid + TPB], v1);
}

// single-block exclusive scan of bhist[NBMAX] -> boff/bcur[0..NBMAX]
__global__ __launch_bounds__(TPB) void bscan(const int* __restrict__ bhist,
                                             int* __restrict__ boff,
                                             int* __restrict__ bcur) {
    __shared__ int lds[TPB];
    int tid = threadIdx.x;
    int a = bhist[2 * tid], b = bhist[2 * tid + 1];
    int s = a + b;
    lds[tid] = s;
    __syncthreads();
    for (int off = 1; off < TPB; off <<= 1) {
        int x = (tid >= off) ? lds[tid - off] : 0;
        __syncthreads();
        lds[tid] += x;
        __syncthreads();
    }
    int excl = lds[tid] - s;
    boff[2 * tid] = excl;       bcur[2 * tid] = excl;
    boff[2 * tid + 1] = excl + a; bcur[2 * tid + 1] = excl + a;
    if (tid == TPB - 1) { boff[NBMAX] = lds[TPB - 1]; bcur[NBMAX] = lds[TPB - 1]; }
}

__global__ __launch_bounds__(TPB) void ms_scatter(const int* __restrict__ src,
                                                  const int* __restrict__ dst,
                                                  int* __restrict__ bcur,
                                                  int2* __restrict__ pairs, int e) {
    __shared__ int h[NBMAX];
    __shared__ int sbase[NBMAX];
    int tid = threadIdx.x;
    h[tid] = 0; h[tid + TPB] = 0;
    __syncthreads();
    int base = blockIdx.x * (TPB * IPT);
#pragma unroll 8
    for (int k = 0; k < IPT; ++k) {
        int i = base + k * TPB + tid;
        if (i < e) atomicAdd(&h[dst[i] >> BSH], 1);
    }
    __syncthreads();
    int v0 = h[tid], v1 = h[tid + TPB];
    if (v0) sbase[tid] = atomicAdd(&bcur[tid], v0);
    if (v1) sbase[tid + TPB] = atomicAdd(&bcur[tid + TPB], v1);
    __syncthreads();
#pragma unroll 8
    for (int k = 0; k < IPT; ++k) {
        int i = base + k * TPB + tid;
        if (i < e) {
            int s = src[i], d = dst[i];
            int pos = atomicAdd(&sbase[d >> BSH], 1);
            pairs[pos] = make_int2(s, d);
        }
    }
}

// one WG per bucket: histogram -> scan -> rowptr/dinv -> csr placement
__global__ __launch_bounds__(TPB) void build_csr(const int2* __restrict__ pairs,
                                                 const int* __restrict__ boff,
                                                 int* __restrict__ rowptr,
                                                 float* __restrict__ dinv,
                                                 int* __restrict__ csr, int n, int e) {
    int b = blockIdx.x;
    int p0 = boff[b], p1 = boff[b + 1];
    __shared__ int scnt[TPB];
    __shared__ int sbase[TPB];
    __shared__ int lds[TPB];
    int tid = threadIdx.x;
    scnt[tid] = 0;
    __syncthreads();
    for (int j = p0 + tid; j < p1; j += TPB)
        atomicAdd(&scnt[pairs[j].y & (TPB - 1)], 1);
    __syncthreads();
    int c = scnt[tid];
    lds[tid] = c;
    __syncthreads();
    for (int off = 1; off < TPB; off <<= 1) {
        int x = (tid >= off) ? lds[tid - off] : 0;
        __syncthreads();
        lds[tid] += x;
        __syncthreads();
    }
    int excl = lds[tid] - c;
    sbase[tid] = p0 + excl;
    int node = (b << BSH) + tid;
    if (node < n) {
        rowptr[node] = p0 + excl;
        dinv[node] = rsqrtf(1.0f + (float)c);  // +1 self-loop
    }
    if (b == 0 && tid == 0) rowptr[n] = e;
    __syncthreads();
    for (int j = p0 + tid; j < p1; j += TPB) {
        int2 pr = pairs[j];
        int pos = atomicAdd(&sbase[pr.y & (TPB - 1)], 1);
        csr[pos] = pr.x;
    }
}

// xs[i][k] = x[i][k] * dinv[i]
template <int K>
__global__ __launch_bounds__(TPB) void prescale(const float* __restrict__ x,
                                                const float* __restrict__ dinv,
                                                float* __restrict__ xs, int n) {
    int idx = blockIdx.x * TPB + threadIdx.x;
    if (idx < n * K) xs[idx] = x[idx] * dinv[idx / K];
}

// ---- aggregation: C lanes per node, unroll-8 gather, one coalesced write ----
template <int C>
__global__ __launch_bounds__(TPB) void agg_kernel(const float* __restrict__ hs,
                                                  const int* __restrict__ rowptr,
                                                  const int* __restrict__ csr,
                                                  const float* __restrict__ dinv,
                                                  float* __restrict__ agg, int n) {
    const int NPB = TPB / C;
    int grp = threadIdx.x / C, c = threadIdx.x % C;
    int i = blockIdx.x * NPB + grp;
    if (i >= n) return;
    int j = rowptr[i], re = rowptr[i + 1];
    float acc = hs[(size_t)i * C + c];  // self-loop term
    float acc2 = 0.0f;
    for (; j + 8 <= re; j += 8) {
        int s0 = csr[j + 0], s1 = csr[j + 1], s2 = csr[j + 2], s3 = csr[j + 3];
        int s4 = csr[j + 4], s5 = csr[j + 5], s6 = csr[j + 6], s7 = csr[j + 7];
        float v0 = hs[(size_t)s0 * C + c], v1 = hs[(size_t)s1 * C + c];
        float v2 = hs[(size_t)s2 * C + c], v3 = hs[(size_t)s3 * C + c];
        float v4 = hs[(size_t)s4 * C + c], v5 = hs[(size_t)s5 * C + c];
        float v6 = hs[(size_t)s6 * C + c], v7 = hs[(size_t)s7 * C + c];
        acc  += (v0 + v1) + (v2 + v3);
        acc2 += (v4 + v5) + (v6 + v7);
    }
    if (j + 4 <= re) {
        int s0 = csr[j + 0], s1 = csr[j + 1], s2 = csr[j + 2], s3 = csr[j + 3];
        acc  += hs[(size_t)s0 * C + c] + hs[(size_t)s1 * C + c];
        acc2 += hs[(size_t)s2 * C + c] + hs[(size_t)s3 * C + c];
        j += 4;
    }
    for (; j < re; ++j) acc += hs[(size_t)csr[j] * C + c];
    agg[(size_t)i * C + c] = (acc + acc2) * dinv[i];
}

// ---- dense transform, register-resident W column, no LDS ----
// lane-channel c = tid % C; node-group g = tid / C; NPT nodes per thread.
// out[i][c] = (relu?)( sum_k in[i][k]*W[k][c] + b[c] ) * (dinv[i] if SCALE)
template <int K, int C, bool RELU_OUT, bool SCALE_OUT>
__global__ __launch_bounds__(TPB) void xw_kernel(const float* __restrict__ in,
                                                 const float* __restrict__ W,
                                                 const float* __restrict__ b,
                                                 const float* __restrict__ dinv,
                                                 float* __restrict__ out, int n) {
    constexpr int GRP = TPB / C;   // node-groups per block
    constexpr int NPT = 4;         // nodes per thread
    int c = threadIdx.x % C;
    int g = threadIdx.x / C;
    int i0 = (blockIdx.x * GRP + g) * NPT;

    float wc[K];
#pragma unroll
    for (int k = 0; k < K; ++k) wc[k] = W[(size_t)k * C + c];  // coalesced per lane

    float acc[NPT];
#pragma unroll
    for (int t = 0; t < NPT; ++t) acc[t] = 0.0f;

#pragma unroll
    for (int t = 0; t < NPT; ++t) {
        int i = i0 + t;
        if (i < n) {
            const float4* row = (const float4*)(in + (size_t)i * K);  // broadcast loads
#pragma unroll
            for (int q = 0; q < K / 4; ++q) {
                float4 r = row[q];
                acc[t] = fmaf(r.x, wc[4 * q + 0], acc[t]);
                acc[t] = fmaf(r.y, wc[4 * q + 1], acc[t]);
                acc[t] = fmaf(r.z, wc[4 * q + 2], acc[t]);
                acc[t] = fmaf(r.w, wc[4 * q + 3], acc[t]);
            }
        }
    }
    float bc = b[c];
#pragma unroll
    for (int t = 0; t < NPT; ++t) {
        int i = i0 + t;
        if (i < n) {
            float v = acc[t] + bc;
            if (RELU_OUT) v = fmaxf(v, 0.0f);
            if (SCALE_OUT) v *= dinv[i];
            out[(size_t)i * C + c] = v;  // coalesced
        }
    }
}

extern "C" void kernel_launch(void* const* d_in, const int* in_sizes, int n_in,
                              void* d_out, int out_size, void* d_ws, size_t ws_size,
                              hipStream_t stream) {
    const float* x  = (const float*)d_in[0];
    const int*   ei = (const int*)d_in[1];
    const float* W1 = (const float*)d_in[2];
    const float* b1 = (const float*)d_in[3];
    const float* W2 = (const float*)d_in[4];
    const float* b2 = (const float*)d_in[5];
    const float* W3 = (const float*)d_in[6];
    const float* b3 = (const float*)d_in[7];
    float* out = (float*)d_out;

    const int n = in_sizes[0] / 4;   // 100000
    const int e = in_sizes[1] / 2;   // 1600000
    const int* src = ei;
    const int* dst = ei + e;
    const int nb = cdiv(n, 1 << BSH);  // 391 buckets (NBMAX=512 slots)

    char* ws = (char*)d_ws;
    size_t off = 0;
    auto carve = [&](size_t bytes) {
        char* p = ws + off;
        off = (off + bytes + 255) & ~(size_t)255;
        return p;
    };
    float* dinv   = (float*)carve((size_t)n * 4);
    int*   rowptr = (int*)  carve((size_t)(n + 1) * 4);
    int*   bhist  = (int*)  carve((size_t)(NBMAX + 1) * 4);
    int*   boff   = (int*)  carve((size_t)(NBMAX + 1) * 4);
    int*   bcur   = (int*)  carve((size_t)(NBMAX + 1) * 4);
    int*   csr    = (int*)  carve((size_t)e * 4);
    float* A      = (float*)carve((size_t)n * 64 * 4);  // agg output; pairs aliases this
    float* B      = (float*)carve((size_t)n * 32 * 4);  // h1s
    float* xs     = (float*)carve((size_t)n * 4 * 4);   // prescaled x
    int2* pairs = (int2*)A;  // 12.8 MB <= 25.6 MB; consumed before A is first written

    const int eblk = cdiv(e, TPB * IPT);  // 196 blocks over edges

    // ---- CSR + norms (LDS-staged multisplit counting sort) ----
    bhist_zero<<<cdiv(NBMAX + 1, TPB), TPB, 0, stream>>>(bhist, NBMAX + 1);
    ms_hist<<<eblk, TPB, 0, stream>>>(dst, bhist, e);
    bscan<<<1, TPB, 0, stream>>>(bhist, boff, bcur);
    ms_scatter<<<eblk, TPB, 0, stream>>>(src, dst, bcur, pairs, e);
    build_csr<<<nb, TPB, 0, stream>>>(pairs, boff, rowptr, dinv, csr, n, e);

    // ---- layer 1: xs = x*dinv; agg C=4; h1s = relu(agg@W1+b1)*dinv [n,32] ----
    prescale<4><<<cdiv((long long)n * 4, TPB), TPB, 0, stream>>>(x, dinv, xs, n);
    agg_kernel<4><<<cdiv(n, TPB / 4), TPB, 0, stream>>>(xs, rowptr, csr, dinv, A, n);
    xw_kernel<4, 32, true, true><<<cdiv(n, (TPB / 32) * 4), TPB, 0, stream>>>(A, W1, b1, dinv, B, n);

    // ---- layer 2: agg C=32; h2s = relu(agg@W2+b2)*dinv [n,64] (in d_out) ----
    agg_kernel<32><<<cdiv(n, TPB / 32), TPB, 0, stream>>>(B, rowptr, csr, dinv, A, n);
    xw_kernel<32, 64, true, true><<<cdiv(n, (TPB / 64) * 4), TPB, 0, stream>>>(A, W2, b2, dinv, out, n);

    // ---- layer 3: agg C=64; out = agg@W3+b3 ----
    agg_kernel<64><<<cdiv(n, TPB / 64), TPB, 0, stream>>>(out, rowptr, csr, dinv, A, n);
    xw_kernel<64, 64, false, false><<<cdiv(n, (TPB / 64) * 4), TPB, 0, stream>>>(A, W3, b3, dinv, out, n);
}

// Round 7
// 270.450 us; speedup vs baseline: 2.7163x; 1.0234x over previous
//
#include <hip/hip_runtime.h>

// 3-layer GCN, pull-mode CSR gather, aggregate-before-transform, prescaled features.
// CSR build = 2-pass LDS-staged multisplit counting sort (bucket = dst>>8).
// xw transform: K tiled in KT=16-register chunks of W-column, NPT=16 nodes'
// accumulators resident in VGPRs -> no W reload per FMA (R6 lesson: wc[K=64]
// exceeded the 52-VGPR allocation and the compiler re-loaded W inside the loop).
// agg: float4 lanes (C/4 lanes per node) -> 4x rows in flight per gather instr.

#define TPB 256
#define BSH 8                 // 256 nodes per bucket
#define NBMAX 512             // LDS histogram slots (nb = 391 actual)
#define IPT 32                // edges per thread -> 8192 edges per block

static inline int cdiv(long long a, int b) { return (int)((a + b - 1) / b); }

__global__ __launch_bounds__(TPB) void bhist_zero(int* __restrict__ bhist, int m) {
    int i = blockIdx.x * TPB + threadIdx.x;
    if (i < m) bhist[i] = 0;
}

__global__ __launch_bounds__(TPB) void ms_hist(const int* __restrict__ dst,
                                               int* __restrict__ bhist, int e) {
    __shared__ int h[NBMAX];
    int tid = threadIdx.x;
    h[tid] = 0; h[tid + TPB] = 0;
    __syncthreads();
    int base = blockIdx.x * (TPB * IPT);
#pragma unroll 8
    for (int k = 0; k < IPT; ++k) {
        int i = base + k * TPB + tid;
        if (i < e) atomicAdd(&h[dst[i] >> BSH], 1);
    }
    __syncthreads();
    int v0 = h[tid], v1 = h[tid + TPB];
    if (v0) atomicAdd(&bhist[tid], v0);
    if (v1) atomicAdd(&bhist[tid + TPB], v1);
}

// single-block exclusive scan of bhist[NBMAX] -> boff/bcur[0..NBMAX]
__global__ __launch_bounds__(TPB) void bscan(const int* __restrict__ bhist,
                                             int* __restrict__ boff,
                                             int* __restrict__ bcur) {
    __shared__ int lds[TPB];
    int tid = threadIdx.x;
    int a = bhist[2 * tid], b = bhist[2 * tid + 1];
    int s = a + b;
    lds[tid] = s;
    __syncthreads();
    for (int off = 1; off < TPB; off <<= 1) {
        int x = (tid >= off) ? lds[tid - off] : 0;
        __syncthreads();
        lds[tid] += x;
        __syncthreads();
    }
    int excl = lds[tid] - s;
    boff[2 * tid] = excl;       bcur[2 * tid] = excl;
    boff[2 * tid + 1] = excl + a; bcur[2 * tid + 1] = excl + a;
    if (tid == TPB - 1) { boff[NBMAX] = lds[TPB - 1]; bcur[NBMAX] = lds[TPB - 1]; }
}

__global__ __launch_bounds__(TPB) void ms_scatter(const int* __restrict__ src,
                                                  const int* __restrict__ dst,
                                                  int* __restrict__ bcur,
                                                  int2* __restrict__ pairs, int e) {
    __shared__ int h[NBMAX];
    __shared__ int sbase[NBMAX];
    int tid = threadIdx.x;
    h[tid] = 0; h[tid + TPB] = 0;
    __syncthreads();
    int base = blockIdx.x * (TPB * IPT);
#pragma unroll 8
    for (int k = 0; k < IPT; ++k) {
        int i = base + k * TPB + tid;
        if (i < e) atomicAdd(&h[dst[i] >> BSH], 1);
    }
    __syncthreads();
    int v0 = h[tid], v1 = h[tid + TPB];
    if (v0) sbase[tid] = atomicAdd(&bcur[tid], v0);
    if (v1) sbase[tid + TPB] = atomicAdd(&bcur[tid + TPB], v1);
    __syncthreads();
#pragma unroll 8
    for (int k = 0; k < IPT; ++k) {
        int i = base + k * TPB + tid;
        if (i < e) {
            int s = src[i], d = dst[i];
            int pos = atomicAdd(&sbase[d >> BSH], 1);
            pairs[pos] = make_int2(s, d);
        }
    }
}

// one WG per bucket: histogram -> scan -> rowptr/dinv -> csr placement
__global__ __launch_bounds__(TPB) void build_csr(const int2* __restrict__ pairs,
                                                 const int* __restrict__ boff,
                                                 int* __restrict__ rowptr,
                                                 float* __restrict__ dinv,
                                                 int* __restrict__ csr, int n, int e) {
    int b = blockIdx.x;
    int p0 = boff[b], p1 = boff[b + 1];
    __shared__ int scnt[TPB];
    __shared__ int sbase[TPB];
    __shared__ int lds[TPB];
    int tid = threadIdx.x;
    scnt[tid] = 0;
    __syncthreads();
    for (int j = p0 + tid; j < p1; j += TPB)
        atomicAdd(&scnt[pairs[j].y & (TPB - 1)], 1);
    __syncthreads();
    int c = scnt[tid];
    lds[tid] = c;
    __syncthreads();
    for (int off = 1; off < TPB; off <<= 1) {
        int x = (tid >= off) ? lds[tid - off] : 0;
        __syncthreads();
        lds[tid] += x;
        __syncthreads();
    }
    int excl = lds[tid] - c;
    sbase[tid] = p0 + excl;
    int node = (b << BSH) + tid;
    if (node < n) {
        rowptr[node] = p0 + excl;
        dinv[node] = rsqrtf(1.0f + (float)c);  // +1 self-loop
    }
    if (b == 0 && tid == 0) rowptr[n] = e;
    __syncthreads();
    for (int j = p0 + tid; j < p1; j += TPB) {
        int2 pr = pairs[j];
        int pos = atomicAdd(&sbase[pr.y & (TPB - 1)], 1);
        csr[pos] = pr.x;
    }
}

// xs[i][k] = x[i][k] * dinv[i]
template <int K>
__global__ __launch_bounds__(TPB) void prescale(const float* __restrict__ x,
                                                const float* __restrict__ dinv,
                                                float* __restrict__ xs, int n) {
    int idx = blockIdx.x * TPB + threadIdx.x;
    if (idx < n * K) xs[idx] = x[idx] * dinv[idx / K];
}

static __device__ __forceinline__ float4 f4add(float4 a, float4 b) {
    return make_float4(a.x + b.x, a.y + b.y, a.z + b.z, a.w + b.w);
}

// ---- aggregation: C/4 float4-lanes per node, unroll-8 gather ----
template <int C>
__global__ __launch_bounds__(TPB) void agg_kernel(const float* __restrict__ hs,
                                                  const int* __restrict__ rowptr,
                                                  const int* __restrict__ csr,
                                                  const float* __restrict__ dinv,
                                                  float* __restrict__ agg, int n) {
    constexpr int L = C / 4;         // float4 lanes per node
    const int NPB = TPB / L;
    int grp = threadIdx.x / L, cl = threadIdx.x % L;
    int i = blockIdx.x * NPB + grp;
    if (i >= n) return;
    const float4* hv = (const float4*)hs;
    float4 acc = hv[(size_t)i * L + cl];  // self-loop term
    float4 acc2 = make_float4(0.f, 0.f, 0.f, 0.f);
    int j = rowptr[i], re = rowptr[i + 1];
    for (; j + 8 <= re; j += 8) {
        int s0 = csr[j + 0], s1 = csr[j + 1], s2 = csr[j + 2], s3 = csr[j + 3];
        int s4 = csr[j + 4], s5 = csr[j + 5], s6 = csr[j + 6], s7 = csr[j + 7];
        float4 v0 = hv[(size_t)s0 * L + cl], v1 = hv[(size_t)s1 * L + cl];
        float4 v2 = hv[(size_t)s2 * L + cl], v3 = hv[(size_t)s3 * L + cl];
        float4 v4 = hv[(size_t)s4 * L + cl], v5 = hv[(size_t)s5 * L + cl];
        float4 v6 = hv[(size_t)s6 * L + cl], v7 = hv[(size_t)s7 * L + cl];
        acc  = f4add(acc,  f4add(f4add(v0, v1), f4add(v2, v3)));
        acc2 = f4add(acc2, f4add(f4add(v4, v5), f4add(v6, v7)));
    }
    if (j + 4 <= re) {
        int s0 = csr[j + 0], s1 = csr[j + 1], s2 = csr[j + 2], s3 = csr[j + 3];
        acc  = f4add(acc,  f4add(hv[(size_t)s0 * L + cl], hv[(size_t)s1 * L + cl]));
        acc2 = f4add(acc2, f4add(hv[(size_t)s2 * L + cl], hv[(size_t)s3 * L + cl]));
        j += 4;
    }
    for (; j < re; ++j) acc = f4add(acc, hv[(size_t)csr[j] * L + cl]);
    float di = dinv[i];
    float4 r = f4add(acc, acc2);
    r.x *= di; r.y *= di; r.z *= di; r.w *= di;
    ((float4*)agg)[(size_t)i * L + cl] = r;
}

// ---- dense transform: K tiled (KT regs of W), NPT node-accs in VGPRs ----
// out[i][c] = (relu?)( sum_k in[i][k]*W[k][c] + b[c] ) * (dinv[i] if SCALE)
template <int K, int C, bool RELU_OUT, bool SCALE_OUT>
__global__ __launch_bounds__(TPB) void xw_kernel(const float* __restrict__ in,
                                                 const float* __restrict__ W,
                                                 const float* __restrict__ b,
                                                 const float* __restrict__ dinv,
                                                 float* __restrict__ out, int n) {
    constexpr int KT = (K > 16) ? 16 : K;  // W-column chunk held in regs
    constexpr int NPT = 16;                // nodes per slot (acc in regs)
    constexpr int SLOTS = TPB / C;
    int c = threadIdx.x % C;
    int slot = threadIdx.x / C;
    int i0 = (blockIdx.x * SLOTS + slot) * NPT;

    float acc[NPT];
#pragma unroll
    for (int t = 0; t < NPT; ++t) acc[t] = 0.0f;

    if (i0 + NPT <= n) {  // guard-free main path
#pragma unroll
        for (int p = 0; p < K; p += KT) {
            float wc[KT];
#pragma unroll
            for (int k = 0; k < KT; ++k) wc[k] = W[(size_t)(p + k) * C + c];
#pragma unroll
            for (int t = 0; t < NPT; ++t) {
                const float4* row = (const float4*)(in + (size_t)(i0 + t) * K + p);
#pragma unroll
                for (int q = 0; q < KT / 4; ++q) {
                    float4 r = row[q];
                    acc[t] = fmaf(r.x, wc[4 * q + 0], acc[t]);
                    acc[t] = fmaf(r.y, wc[4 * q + 1], acc[t]);
                    acc[t] = fmaf(r.z, wc[4 * q + 2], acc[t]);
                    acc[t] = fmaf(r.w, wc[4 * q + 3], acc[t]);
                }
            }
        }
        float bc = b[c];
#pragma unroll
        for (int t = 0; t < NPT; ++t) {
            float v = acc[t] + bc;
            if (RELU_OUT) v = fmaxf(v, 0.0f);
            if (SCALE_OUT) v *= dinv[i0 + t];
            out[(size_t)(i0 + t) * C + c] = v;
        }
    } else if (i0 < n) {  // tail block
#pragma unroll
        for (int p = 0; p < K; p += KT) {
            float wc[KT];
#pragma unroll
            for (int k = 0; k < KT; ++k) wc[k] = W[(size_t)(p + k) * C + c];
            for (int t = 0; t < NPT; ++t) {
                int i = i0 + t;
                if (i >= n) break;
                const float4* row = (const float4*)(in + (size_t)i * K + p);
#pragma unroll
                for (int q = 0; q < KT / 4; ++q) {
                    float4 r = row[q];
                    acc[t] = fmaf(r.x, wc[4 * q + 0], acc[t]);
                    acc[t] = fmaf(r.y, wc[4 * q + 1], acc[t]);
                    acc[t] = fmaf(r.z, wc[4 * q + 2], acc[t]);
                    acc[t] = fmaf(r.w, wc[4 * q + 3], acc[t]);
                }
            }
        }
        float bc = b[c];
        for (int t = 0; t < NPT; ++t) {
            int i = i0 + t;
            if (i >= n) break;
            float v = acc[t] + bc;
            if (RELU_OUT) v = fmaxf(v, 0.0f);
            if (SCALE_OUT) v *= dinv[i];
            out[(size_t)i * C + c] = v;
        }
    }
}

extern "C" void kernel_launch(void* const* d_in, const int* in_sizes, int n_in,
                              void* d_out, int out_size, void* d_ws, size_t ws_size,
                              hipStream_t stream) {
    const float* x  = (const float*)d_in[0];
    const int*   ei = (const int*)d_in[1];
    const float* W1 = (const float*)d_in[2];
    const float* b1 = (const float*)d_in[3];
    const float* W2 = (const float*)d_in[4];
    const float* b2 = (const float*)d_in[5];
    const float* W3 = (const float*)d_in[6];
    const float* b3 = (const float*)d_in[7];
    float* out = (float*)d_out;

    const int n = in_sizes[0] / 4;   // 100000
    const int e = in_sizes[1] / 2;   // 1600000
    const int* src = ei;
    const int* dst = ei + e;
    const int nb = cdiv(n, 1 << BSH);  // 391 buckets (NBMAX=512 slots)

    char* ws = (char*)d_ws;
    size_t off = 0;
    auto carve = [&](size_t bytes) {
        char* p = ws + off;
        off = (off + bytes + 255) & ~(size_t)255;
        return p;
    };
    float* dinv   = (float*)carve((size_t)n * 4);
    int*   rowptr = (int*)  carve((size_t)(n + 1) * 4);
    int*   bhist  = (int*)  carve((size_t)(NBMAX + 1) * 4);
    int*   boff   = (int*)  carve((size_t)(NBMAX + 1) * 4);
    int*   bcur   = (int*)  carve((size_t)(NBMAX + 1) * 4);
    int*   csr    = (int*)  carve((size_t)e * 4);
    float* A      = (float*)carve((size_t)n * 64 * 4);  // agg output; pairs aliases this
    float* B      = (float*)carve((size_t)n * 32 * 4);  // h1s
    float* xs     = (float*)carve((size_t)n * 4 * 4);   // prescaled x
    int2* pairs = (int2*)A;  // 12.8 MB <= 25.6 MB; consumed before A is first written

    const int eblk = cdiv(e, TPB * IPT);  // 196 blocks over edges

    // ---- CSR + norms (LDS-staged multisplit counting sort) ----
    bhist_zero<<<cdiv(NBMAX + 1, TPB), TPB, 0, stream>>>(bhist, NBMAX + 1);
    ms_hist<<<eblk, TPB, 0, stream>>>(dst, bhist, e);
    bscan<<<1, TPB, 0, stream>>>(bhist, boff, bcur);
    ms_scatter<<<eblk, TPB, 0, stream>>>(src, dst, bcur, pairs, e);
    build_csr<<<nb, TPB, 0, stream>>>(pairs, boff, rowptr, dinv, csr, n, e);

    // ---- layer 1: xs = x*dinv; agg C=4; h1s = relu(agg@W1+b1)*dinv [n,32] ----
    prescale<4><<<cdiv((long long)n * 4, TPB), TPB, 0, stream>>>(x, dinv, xs, n);
    agg_kernel<4><<<cdiv(n, TPB / 1), TPB, 0, stream>>>(xs, rowptr, csr, dinv, A, n);
    xw_kernel<4, 32, true, true><<<cdiv(n, (TPB / 32) * 16), TPB, 0, stream>>>(A, W1, b1, dinv, B, n);

    // ---- layer 2: agg C=32; h2s = relu(agg@W2+b2)*dinv [n,64] (in d_out) ----
    agg_kernel<32><<<cdiv(n, TPB / 8), TPB, 0, stream>>>(B, rowptr, csr, dinv, A, n);
    xw_kernel<32, 64, true, true><<<cdiv(n, (TPB / 64) * 16), TPB, 0, stream>>>(A, W2, b2, dinv, out, n);

    // ---- layer 3: agg C=64; out = agg@W3+b3 ----
    agg_kernel<64><<<cdiv(n, TPB / 16), TPB, 0, stream>>>(out, rowptr, csr, dinv, A, n);
    xw_kernel<64, 64, false, false><<<cdiv(n, (TPB / 64) * 16), TPB, 0, stream>>>(A, W3, b3, dinv, out, n);
}